// Round 3
// baseline (148.589 us; speedup 1.0000x reference)
//
#include <hip/hip_runtime.h>

#define NQ 12
#define NLAYERS 8
#define BATCH 1024

typedef float v2f __attribute__((ext_vector_type(2)));

// ---------------------------------------------------------------------------
// CNOT folding (unchanged math from R2, verified): phys[p] = psi[L p], L = P^l.
//   RX(w) partner mask:  M_w(l) = { w+j : C(l,j) odd }
//   RZ(w) sign row:      R_w(l) = { w-j : C(l+j-1,j) odd }
// NEW physical placement (4 waves per state):
//   p = (wq<<10)|(lane<<4)|j ; wire0 = wq bit1, wire1 = wq bit0,
//   wires 2..7 = lane bits 5..0, wires 8..11 = j bits 3..0.
//   (wire w == global index bit 11-w, same convention as before)
// ---------------------------------------------------------------------------

constexpr bool codd(int n,int k){ return k==0 || (n>=0 && (k & ~n)==0); }
constexpr int Mwire(int l,int w){ int m=0; for(int j=0; w+j<=11; ++j) if(codd(l,j)) m|=1<<(w+j); return m; }
constexpr int Rwire(int l,int w){ int m=0; for(int j=0; j<=w; ++j) if(codd(l+j-1,j)) m|=1<<(w-j); return m; }
constexpr int wqOf(int wm){ return ((wm&1)<<1) | ((wm>>1)&1); }
constexpr int laneOf(int wm){ int r=0; for(int w=2;w<=7;++w) if((wm>>w)&1) r|=1<<(7-w); return r; }
constexpr int jOf(int wm){ int r=0; for(int w=8;w<=11;++w) if((wm>>w)&1) r|=1<<(11-w); return r; }
constexpr int hbit(int m){ int h=0; while(m>>(h+1)) ++h; return 1<<h; }

__device__ __forceinline__ float bperm(int addr, float v){
    return __int_as_float(__builtin_amdgcn_ds_bpermute(addr, __float_as_int(v)));
}

// a' = hc*a + hs*(p.y, -p.x)   (RX butterfly contribution, packed)
__device__ __forceinline__ v2f rot(v2f a, v2f p, float hc, float hs){
    v2f sw; sw.x = p.y; sw.y = -p.x;
    return hc*a + hs*sw;
}

template<int JM>
__device__ __forceinline__ void rx_local(v2f (&a)[16], float hc, float hs){
    constexpr int HB = hbit(JM);
    #pragma unroll
    for (int j=0;j<16;++j){
        if (j & HB) continue;
        const int j2 = j ^ JM;
        v2f u = a[j], v = a[j2];
        a[j]  = rot(u, v, hc, hs);
        a[j2] = rot(v, u, hc, hs);
    }
}

template<int LM,int JM>
__device__ __forceinline__ void rx_cross(v2f (&a)[16], float hc, float hs, int lane){
    const int addr = ((lane ^ LM) & 63) << 2;
    if constexpr (JM == 0){
        #pragma unroll
        for (int j=0;j<16;++j){
            v2f p; p.x = bperm(addr, a[j].x); p.y = bperm(addr, a[j].y);
            a[j] = rot(a[j], p, hc, hs);
        }
    } else {
        constexpr int HB = hbit(JM);
        #pragma unroll
        for (int j=0;j<16;++j){
            if (j & HB) continue;
            const int j2 = j ^ JM;
            v2f u = a[j], v = a[j2];
            v2f pu; pu.x = bperm(addr, v.x); pu.y = bperm(addr, v.y);  // partner's old a[j2]
            v2f pv; pv.x = bperm(addr, u.x); pv.y = bperm(addr, u.y);  // partner's old a[j]
            a[j]  = rot(u, pu, hc, hs);
            a[j2] = rot(v, pv, hc, hs);
        }
    }
}

// partner in another wave: full-state exchange through LDS ([wq][j][lane] v2f, b64 conflict-free)
template<int WQM,int LM,int JM>
__device__ __forceinline__ void rx_wave(v2f (&a)[16], float hc, float hs,
                                        int lane, int wq, v2f* lds){
    v2f* wr = lds + (wq*16)*64 + lane;
    #pragma unroll
    for (int j=0;j<16;++j) wr[j*64] = a[j];
    __syncthreads();
    const v2f* rd = lds + ((wq^WQM)*16)*64 + ((lane^LM)&63);
    #pragma unroll
    for (int j=0;j<16;++j){
        v2f p = rd[(j^JM)*64];
        a[j] = rot(a[j], p, hc, hs);
    }
    __syncthreads();
}

template<int RW>
__device__ __forceinline__ void rz_gate(v2f (&a)[16], float hc, float hs, int lane, int wq){
    constexpr int WQ = wqOf(RW), LM = laneOf(RW), JM = jOf(RW);
    int par = __popc(lane & LM);
    if constexpr (WQ) par ^= __popc(wq & WQ);
    const float hp = (par & 1) ? -hs : hs;
    const float hn = -hp;
    #pragma unroll
    for (int j=0;j<16;++j){
        const float s = (__builtin_popcount(j & JM) & 1) ? hn : hp;  // compile-time select
        v2f u = a[j];
        v2f sw; sw.x = u.y; sw.y = -u.x;
        a[j] = hc*u + s*sw;
    }
}

template<int L,int W>
__device__ __forceinline__ void wire_gates(v2f (&a)[16], const float4* __restrict__ tbl,
                                           int lane, int wq, v2f* lds){
    const float4 t = tbl[(L-1)*NQ + W];     // uniform -> s_load_dwordx4
    constexpr int M  = Mwire(L,W);
    constexpr int WQ = wqOf(M), LM = laneOf(M), JM = jOf(M);
    if constexpr (WQ)      rx_wave<WQ,LM,JM>(a, t.x, t.y, lane, wq, lds);
    else if constexpr (LM) rx_cross<LM,JM>(a, t.x, t.y, lane);
    else                   rx_local<JM>(a, t.x, t.y);
    rz_gate<Rwire(L,W)>(a, t.z, t.w, lane, wq);
    if constexpr (W+1 < NQ) wire_gates<L,W+1>(a, tbl, lane, wq, lds);
}

template<int W>
__device__ __forceinline__ void init_rx(v2f (&a)[16], const float* __restrict__ xb,
                                        int lane, int wq, v2f* lds){
    float hs, hc;
    __sincosf(xb[W]*1.5707963267948966f, &hs, &hc);
    if constexpr (W == 0)      rx_wave<2,0,0>(a, hc, hs, lane, wq, lds);
    else if constexpr (W == 1) rx_wave<1,0,0>(a, hc, hs, lane, wq, lds);
    else if constexpr (W <= 7) rx_cross<(1<<(7-W)),0>(a, hc, hs, lane);
    else                       rx_local<(1<<(11-W))>(a, hc, hs);
    if constexpr (W+1 < NQ) init_rx<W+1>(a, xb, lane, wq, lds);
}

template<int L>
__device__ __forceinline__ void run_layers(v2f (&a)[16], const float4* __restrict__ tbl,
                                           int lane, int wq, v2f* lds){
    wire_gates<L,0>(a, tbl, lane, wq, lds);
    if constexpr (L < NLAYERS) run_layers<L+1>(a, tbl, lane, wq, lds);
}

__global__ void prep_kernel(const float* __restrict__ P, float4* __restrict__ tbl){
    const int i = threadIdx.x;
    if (i < NLAYERS*NQ){
        float4 v;
        __sincosf(P[2*i]   * 0.5f, &v.y, &v.x);   // RX: (cos, sin)
        __sincosf(P[2*i+1] * 0.5f, &v.w, &v.z);   // RZ: (cos, sin)
        tbl[i] = v;
    }
}

__global__ __launch_bounds__(256, 4) void qnn_kernel(const float* __restrict__ x,
                                                     const float4* __restrict__ tbl,
                                                     const float* __restrict__ Wm,
                                                     float* __restrict__ out)
{
    __shared__ v2f lds[4*16*64];
    const int lane = threadIdx.x & 63;
    const int wq   = threadIdx.x >> 6;
    const int b    = blockIdx.x;

    v2f a[16];
    #pragma unroll
    for (int j=0;j<16;++j){ a[j].x = 0.f; a[j].y = 0.f; }
    if (threadIdx.x == 0) a[0].x = 1.0f;

    init_rx<0>(a, x + b*NQ, lane, wq, lds);
    run_layers<1>(a, tbl, lane, wq, lds);

    // ---- PauliZ expvals under final L = P^8: row_w = e_w ^ e_{w-8} ----
    float s0=0.f, sj3=0.f, sj2=0.f, sj1=0.f, sj0=0.f;
    #pragma unroll
    for (int j=0;j<16;++j){
        float pr = fmaf(a[j].x, a[j].x, a[j].y*a[j].y);
        s0  += pr;
        sj3 += (j&8)? -pr : pr;   // wire 8 local part
        sj2 += (j&4)? -pr : pr;   // wire 9
        sj1 += (j&2)? -pr : pr;   // wire 10
        sj0 += (j&1)? -pr : pr;   // wire 11
    }
    float z[12];
    z[0] = (wq&2) ? -s0 : s0;                 // wire0 = wq bit1
    z[1] = (wq&1) ? -s0 : s0;                 // wire1 = wq bit0
    #pragma unroll
    for (int w=2; w<=7; ++w) z[w] = ((lane>>(7-w))&1) ? -s0 : s0;
    z[8]  = (wq&2)          ? -sj3 : sj3;     // ^ wire0
    z[9]  = (wq&1)          ? -sj2 : sj2;     // ^ wire1
    z[10] = ((lane>>5)&1)   ? -sj1 : sj1;     // ^ wire2
    z[11] = ((lane>>4)&1)   ? -sj0 : sj0;     // ^ wire3

    #pragma unroll
    for (int m=1; m<64; m<<=1){
        #pragma unroll
        for (int w=0; w<12; ++w) z[w] += __shfl_xor(z[w], m, 64);
    }

    // cross-wave combine + linear head
    float* sh = (float*)lds;
    if (lane == 0){
        #pragma unroll
        for (int w=0; w<12; ++w) sh[wq*12 + w] = z[w];
    }
    __syncthreads();
    if (wq == 0){
        float t = 0.f;
        if (lane < 12){
            #pragma unroll
            for (int w=0; w<12; ++w){
                float zz = sh[w] + sh[12+w] + sh[24+w] + sh[36+w];
                t = fmaf(zz, Wm[w*12 + lane], t);
            }
            t = fmaxf(t, 0.f);
        }
        #pragma unroll
        for (int m=1; m<16; m<<=1) t += __shfl_xor(t, m, 64);
        if (lane == 0) out[b] = t;
    }
}

extern "C" void kernel_launch(void* const* d_in, const int* in_sizes, int n_in,
                              void* d_out, int out_size, void* d_ws, size_t ws_size,
                              hipStream_t stream) {
    const float* x  = (const float*)d_in[0];
    const float* P  = (const float*)d_in[1];
    const float* Wm = (const float*)d_in[2];
    float* out = (float*)d_out;
    float4* tbl = (float4*)d_ws;   // 96 * 16 B = 1536 B
    prep_kernel<<<1, 128, 0, stream>>>(P, tbl);
    qnn_kernel<<<BATCH, 256, 0, stream>>>(x, tbl, Wm, out);
}

// Round 4
// 113.348 us; speedup vs baseline: 1.3109x; 1.3109x over previous
//
#include <hip/hip_runtime.h>

#define NQ 12
#define NLAYERS 8
#define BATCH 1024

typedef float v2f __attribute__((ext_vector_type(2)));

// ---------------------------------------------------------------------------
// CNOT folding (verified R2): phys[p] = psi[L p], L = P^l.
//   RX(w) partner mask:  M_w(l) = { w+j : C(l,j) odd }
//   RZ(w) sign row:      R_w(l) = { w-j : C(l+j-1,j) odd }
// Placement (2 waves/state): p = (wv<<11)|(lane<<5)|j
//   wire0 = wv, wires1..6 = lane bits 5..0, wires7..11 = j bits 4..0.
// SoA packing: j = 2t+k ; re2[t] holds re of amps (2t, 2t+1), im2[t] likewise.
//   -> j-space mask JM: m = JM>>1 acts on t, JM&1 = component swap.
// ---------------------------------------------------------------------------

constexpr bool codd(int n,int k){ return k==0 || (n>=0 && (k & ~n)==0); }
constexpr int Mwire(int l,int w){ int m=0; for(int j=0; w+j<=11; ++j) if(codd(l,j)) m|=1<<(w+j); return m; }
constexpr int Rwire(int l,int w){ int m=0; for(int j=0; j<=w; ++j) if(codd(l+j-1,j)) m|=1<<(w-j); return m; }
constexpr int laneOf(int wm){ int r=0; for(int w=1;w<=6;++w) if((wm>>w)&1) r|=1<<(6-w); return r; }
constexpr int jOf(int wm){ int r=0; for(int w=7;w<=11;++w) if((wm>>w)&1) r|=1<<(11-w); return r; }
constexpr int hbit(int m){ int h=0; while(m>>(h+1)) ++h; return 1<<h; }

__device__ __forceinline__ v2f vsplat(float s){ v2f v; v.x=s; v.y=s; return v; }
__device__ __forceinline__ v2f vswap(v2f v){ return __builtin_shufflevector(v, v, 1, 0); }
template<int S> __device__ __forceinline__ v2f msw(v2f v){ if constexpr (S) return vswap(v); else return v; }
__device__ __forceinline__ v2f vfma(v2f a, v2f b, v2f c){ return __builtin_elementwise_fma(a,b,c); }

__device__ __forceinline__ v2f bperm2(int addr, v2f v){
    v2f r;
    r.x = __int_as_float(__builtin_amdgcn_ds_bpermute(addr, __float_as_int(v.x)));
    r.y = __int_as_float(__builtin_amdgcn_ds_bpermute(addr, __float_as_int(v.y)));
    return r;
}

// ---- RX, partner fully local ----
template<int JM>
__device__ __forceinline__ void rx_local(v2f (&re2)[16], v2f (&im2)[16], float hc, float hs){
    const v2f hc2 = vsplat(hc), hs2 = vsplat(hs), ns2 = vsplat(-hs);
    if constexpr (JM == 1){
        #pragma unroll
        for (int t=0;t<16;++t){
            v2f r=re2[t], i=im2[t];
            re2[t] = vfma(hc2, r, hs2*vswap(i));
            im2[t] = vfma(hc2, i, ns2*vswap(r));
        }
    } else {
        constexpr int m = JM>>1, HB = hbit(m);
        #pragma unroll
        for (int t=0;t<16;++t){
            if (t & HB) continue;
            const int t2 = t ^ m;
            v2f ru=re2[t], iu=im2[t], rv=re2[t2], iv=im2[t2];
            re2[t ] = vfma(hc2, ru, hs2*msw<JM&1>(iv));
            im2[t ] = vfma(hc2, iu, ns2*msw<JM&1>(rv));
            re2[t2] = vfma(hc2, rv, hs2*msw<JM&1>(iu));
            im2[t2] = vfma(hc2, iv, ns2*msw<JM&1>(ru));
        }
    }
}

// ---- RX, partner in another lane (same wave) ----
template<int LM,int JM>
__device__ __forceinline__ void rx_cross(v2f (&re2)[16], v2f (&im2)[16], float hc, float hs, int lane){
    const int addr = ((lane ^ LM) & 63) << 2;
    const v2f hc2 = vsplat(hc), hs2 = vsplat(hs), ns2 = vsplat(-hs);
    if constexpr ((JM>>1) == 0){
        #pragma unroll
        for (int t=0;t<16;++t){
            v2f r=re2[t], i=im2[t];
            v2f pi = bperm2(addr, msw<JM&1>(i));
            v2f pr = bperm2(addr, msw<JM&1>(r));
            re2[t] = vfma(hc2, r, hs2*pi);
            im2[t] = vfma(hc2, i, ns2*pr);
        }
    } else {
        constexpr int m = JM>>1, HB = hbit(m);
        #pragma unroll
        for (int t=0;t<16;++t){
            if (t & HB) continue;
            const int t2 = t ^ m;
            v2f ru=re2[t], iu=im2[t], rv=re2[t2], iv=im2[t2];
            v2f piu = bperm2(addr, msw<JM&1>(iv));
            v2f pru = bperm2(addr, msw<JM&1>(rv));
            v2f piv = bperm2(addr, msw<JM&1>(iu));
            v2f prv = bperm2(addr, msw<JM&1>(ru));
            re2[t ] = vfma(hc2, ru, hs2*piu);
            im2[t ] = vfma(hc2, iu, ns2*pru);
            re2[t2] = vfma(hc2, rv, hs2*piv);
            im2[t2] = vfma(hc2, iv, ns2*prv);
        }
    }
}

// ---- RX, partner in the other wave: LDS full-state exchange ----
// lds layout: v2f lds[2(wv)][32(t:0-15=re,16-31=im)][64(lane)]
template<int LM,int JM>
__device__ __forceinline__ void rx_wave(v2f (&re2)[16], v2f (&im2)[16], float hc, float hs,
                                        int lane, int wv, v2f* lds){
    const v2f hc2 = vsplat(hc), hs2 = vsplat(hs), ns2 = vsplat(-hs);
    v2f* wr = lds + (wv*32)*64 + lane;
    #pragma unroll
    for (int t=0;t<16;++t){ wr[t*64] = re2[t]; wr[(16+t)*64] = im2[t]; }
    __syncthreads();
    const v2f* rd = lds + ((wv^1)*32)*64 + ((lane ^ LM) & 63);
    constexpr int m = JM>>1;
    #pragma unroll
    for (int t=0;t<16;++t){
        v2f pr = msw<JM&1>(rd[(t^m)*64]);
        v2f pi = msw<JM&1>(rd[(16+(t^m))*64]);
        re2[t] = vfma(hc2, re2[t], hs2*pi);
        im2[t] = vfma(hc2, im2[t], ns2*pr);
    }
    __syncthreads();
}

// ---- RZ (diagonal) ----
template<int RW>
__device__ __forceinline__ void rz_gate(v2f (&re2)[16], v2f (&im2)[16], float hc, float hs,
                                        int lane, int wv){
    constexpr int LM = laneOf(RW), JM = jOf(RW), WV = RW & 1;
    int par = __popc(lane & LM);
    if constexpr (WV) par ^= wv;
    const float hp = (par & 1) ? -hs : hs;
    const float hq = (JM & 1) ? -hp : hp;
    v2f A;  A.x = hp;   A.y = hq;
    v2f nA; nA.x = -hp; nA.y = -hq;
    const v2f hc2 = vsplat(hc);
    constexpr int m = JM >> 1;
    #pragma unroll
    for (int t=0;t<16;++t){
        const bool odd = __builtin_popcount(t & m) & 1;   // compile-time
        const v2f SV = odd ? nA : A;
        const v2f SN = odd ? A : nA;
        v2f r = re2[t], i = im2[t];
        re2[t] = vfma(hc2, r, SV*i);
        im2[t] = vfma(hc2, i, SN*r);
    }
}

template<int L,int W>
__device__ __forceinline__ void wire_gates(v2f (&re2)[16], v2f (&im2)[16],
                                           const float4* __restrict__ tbl,
                                           int lane, int wv, v2f* lds){
    const float4 t = tbl[(L-1)*NQ + W];       // uniform -> s_load_dwordx4
    constexpr int M  = Mwire(L,W);
    constexpr int LM = laneOf(M), JM = jOf(M);
    if constexpr (M & 1)    rx_wave<LM,JM>(re2,im2,t.x,t.y,lane,wv,lds);
    else if constexpr (LM)  rx_cross<LM,JM>(re2,im2,t.x,t.y,lane);
    else                    rx_local<JM>(re2,im2,t.x,t.y);
    rz_gate<Rwire(L,W)>(re2,im2,t.z,t.w,lane,wv);
    if constexpr (W+1 < NQ) wire_gates<L,W+1>(re2,im2,tbl,lane,wv,lds);
}

template<int W>
__device__ __forceinline__ void init_rx(v2f (&re2)[16], v2f (&im2)[16],
                                        const float* __restrict__ xb,
                                        int lane, int wv, v2f* lds){
    float hs, hc;
    __sincosf(xb[W]*1.5707963267948966f, &hs, &hc);
    if constexpr (W == 0)      rx_wave<0,0>(re2,im2,hc,hs,lane,wv,lds);
    else if constexpr (W <= 6) rx_cross<(1<<(6-W)),0>(re2,im2,hc,hs,lane);
    else                       rx_local<(1<<(11-W))>(re2,im2,hc,hs);
    if constexpr (W+1 < NQ) init_rx<W+1>(re2,im2,xb,lane,wv,lds);
}

template<int L>
__device__ __forceinline__ void run_layers(v2f (&re2)[16], v2f (&im2)[16],
                                           const float4* __restrict__ tbl,
                                           int lane, int wv, v2f* lds){
    wire_gates<L,0>(re2,im2,tbl,lane,wv,lds);
    if constexpr (L < NLAYERS) run_layers<L+1>(re2,im2,tbl,lane,wv,lds);
}

__global__ void prep_kernel(const float* __restrict__ P, float4* __restrict__ tbl){
    const int i = threadIdx.x;
    if (i < NLAYERS*NQ){
        float4 v;
        __sincosf(P[2*i]   * 0.5f, &v.y, &v.x);   // RX: (cos, sin)
        __sincosf(P[2*i+1] * 0.5f, &v.w, &v.z);   // RZ: (cos, sin)
        tbl[i] = v;
    }
}

__global__ __launch_bounds__(128, 2) void qnn_kernel(const float* __restrict__ x,
                                                     const float4* __restrict__ tbl,
                                                     const float* __restrict__ Wm,
                                                     float* __restrict__ out)
{
    __shared__ v2f lds[2*32*64];
    const int lane = threadIdx.x & 63;
    const int wv   = threadIdx.x >> 6;
    const int b    = blockIdx.x;

    v2f re2[16], im2[16];
    #pragma unroll
    for (int t=0;t<16;++t){ re2[t] = vsplat(0.f); im2[t] = vsplat(0.f); }
    if (threadIdx.x == 0) re2[0].x = 1.0f;

    init_rx<0>(re2, im2, x + b*NQ, lane, wv, lds);
    run_layers<1>(re2, im2, tbl, lane, wv, lds);

    // ---- PauliZ expvals; final L = P^8 => row_w = e_w ^ e_{w-8} ----
    v2f S = vsplat(0.f), S7 = vsplat(0.f), S8 = vsplat(0.f), S9 = vsplat(0.f), S10 = vsplat(0.f);
    #pragma unroll
    for (int t=0;t<16;++t){
        v2f p2 = vfma(re2[t], re2[t], im2[t]*im2[t]);
        S += p2;
        S7  += (t&8)? -p2 : p2;   // wire 7  (j bit4)
        S8  += (t&4)? -p2 : p2;   // wire 8  (j bit3)
        S9  += (t&2)? -p2 : p2;   // wire 9  (j bit2)
        S10 += (t&1)? -p2 : p2;   // wire 10 (j bit1)
    }
    const float s0   = S.x + S.y;
    const float sw7  = S7.x + S7.y;
    const float sw8  = S8.x + S8.y;
    const float sw9  = S9.x + S9.y;
    const float sw10 = S10.x + S10.y;
    const float sw11 = S.x - S.y;             // wire 11 (j bit0 = component)

    float z[12];
    z[0] = wv ? -s0 : s0;
    #pragma unroll
    for (int w=1; w<=6; ++w) z[w] = ((lane >> (6-w)) & 1) ? -s0 : s0;
    z[7]  = sw7;
    z[8]  = wv            ? -sw8  : sw8;      // ^ wire0
    z[9]  = ((lane>>5)&1) ? -sw9  : sw9;      // ^ wire1
    z[10] = ((lane>>4)&1) ? -sw10 : sw10;     // ^ wire2
    z[11] = ((lane>>3)&1) ? -sw11 : sw11;     // ^ wire3

    #pragma unroll
    for (int m=1; m<64; m<<=1){
        #pragma unroll
        for (int w=0; w<12; ++w) z[w] += __shfl_xor(z[w], m, 64);
    }

    float* sh = (float*)lds;
    if (lane == 0){
        #pragma unroll
        for (int w=0; w<12; ++w) sh[wv*12 + w] = z[w];
    }
    __syncthreads();
    if (wv == 0){
        float t = 0.f;
        if (lane < 12){
            #pragma unroll
            for (int w=0; w<12; ++w){
                float zz = sh[w] + sh[12+w];
                t = fmaf(zz, Wm[w*12 + lane], t);
            }
            t = fmaxf(t, 0.f);
        }
        #pragma unroll
        for (int m=1; m<16; m<<=1) t += __shfl_xor(t, m, 64);
        if (lane == 0) out[b] = t;
    }
}

extern "C" void kernel_launch(void* const* d_in, const int* in_sizes, int n_in,
                              void* d_out, int out_size, void* d_ws, size_t ws_size,
                              hipStream_t stream) {
    const float* x  = (const float*)d_in[0];
    const float* P  = (const float*)d_in[1];
    const float* Wm = (const float*)d_in[2];
    float* out = (float*)d_out;
    float4* tbl = (float4*)d_ws;   // 96 * 16 B = 1536 B
    prep_kernel<<<1, 128, 0, stream>>>(P, tbl);
    qnn_kernel<<<BATCH, 128, 0, stream>>>(x, tbl, Wm, out);
}

// Round 5
// 96.485 us; speedup vs baseline: 1.5400x; 1.1748x over previous
//
#include <hip/hip_runtime.h>

#define NQ 12
#define NLAYERS 8
#define BATCH 1024

typedef float v2f __attribute__((ext_vector_type(2)));

// ---------------------------------------------------------------------------
// CNOT folding (verified R2/R4): phys[p] = psi[L p], L = P^l.
//   RX(w) partner mask:  M_w(l) = { w+j : C(l,j) odd }
//   RZ(w) sign row:      R_w(l) = { w-j : C(l+j-1,j) odd }
// Placement (2 waves/state): p = (wv<<11)|(lane<<5)|j
//   wire0 = wv, wires1..6 = lane bits 5..0, wires7..11 = j bits 4..0.
// SoA packing: j = 2t+k ; re2[t] holds re of amps (2t,2t+1), im2[t] likewise.
// Transport selection per gate (this round's change):
//   wire0 in mask          -> LDS full exchange (1/layer, unavoidable)
//   wire1|wire2 in mask    -> ds_bpermute (lane xor 32/16, not DPP-able)
//   other lane bits (<=15) -> v_mov_dpp chains on the VALU pipe (4 gates/layer)
//   j-only                 -> register-local
// ---------------------------------------------------------------------------

constexpr bool codd(int n,int k){ return k==0 || (n>=0 && (k & ~n)==0); }
constexpr int Mwire(int l,int w){ int m=0; for(int j=0; w+j<=11; ++j) if(codd(l,j)) m|=1<<(w+j); return m; }
constexpr int Rwire(int l,int w){ int m=0; for(int j=0; j<=w; ++j) if(codd(l+j-1,j)) m|=1<<(w-j); return m; }
constexpr int laneOf(int wm){ int r=0; for(int w=1;w<=6;++w) if((wm>>w)&1) r|=1<<(6-w); return r; }
constexpr int jOf(int wm){ int r=0; for(int w=7;w<=11;++w) if((wm>>w)&1) r|=1<<(11-w); return r; }
constexpr int hbit(int m){ int h=0; while(m>>(h+1)) ++h; return 1<<h; }

__device__ __forceinline__ v2f vsplat(float s){ v2f v; v.x=s; v.y=s; return v; }
__device__ __forceinline__ v2f vswap(v2f v){ return __builtin_shufflevector(v, v, 1, 0); }
template<int S> __device__ __forceinline__ v2f msw(v2f v){ if constexpr (S) return vswap(v); else return v; }
__device__ __forceinline__ v2f vfma(v2f a, v2f b, v2f c){ return __builtin_elementwise_fma(a,b,c); }

__device__ __forceinline__ v2f bperm2(int addr, v2f v){
    v2f r;
    r.x = __int_as_float(__builtin_amdgcn_ds_bpermute(addr, __float_as_int(v.x)));
    r.y = __int_as_float(__builtin_amdgcn_ds_bpermute(addr, __float_as_int(v.y)));
    return r;
}

// ---- DPP lane-xor (VALU pipe), LM in [1,15] ----
template<int CTRL>
__device__ __forceinline__ float dpp1(float v){
    int i = __float_as_int(v);
    return __int_as_float(__builtin_amdgcn_update_dpp(i, i, CTRL, 0xF, 0xF, true));
}
template<int LM>
__device__ __forceinline__ float dppx(float v){
    static_assert(LM >= 1 && LM <= 15, "dpp xor range");
    constexpr int h = (LM >> 2) & 3;
    float r = v;
    if constexpr (h == 1 || h == 2) r = dpp1<0x141>(r);   // row_half_mirror = xor 7
    if constexpr (h == 3 || h == 2) r = dpp1<0x140>(r);   // row_mirror      = xor 15
    constexpr int st = (h==1)?7 : (h==2)?8 : (h==3)?15 : 0;
    constexpr int q = (LM ^ st) & 3;
    if constexpr (q == 1) r = dpp1<0xB1>(r);              // quad_perm xor 1
    if constexpr (q == 2) r = dpp1<0x4E>(r);              // quad_perm xor 2
    if constexpr (q == 3) r = dpp1<0x1B>(r);              // quad_perm xor 3
    return r;
}
template<int LM>
__device__ __forceinline__ v2f dppx2(v2f v){
    v2f r; r.x = dppx<LM>(v.x); r.y = dppx<LM>(v.y); return r;
}

// ---- RX, partner fully local ----
template<int JM>
__device__ __forceinline__ void rx_local(v2f (&re2)[16], v2f (&im2)[16], float hc, float hs){
    const v2f hc2 = vsplat(hc), hs2 = vsplat(hs), ns2 = vsplat(-hs);
    if constexpr (JM == 1){
        #pragma unroll
        for (int t=0;t<16;++t){
            v2f r=re2[t], i=im2[t];
            re2[t] = vfma(hc2, r, hs2*vswap(i));
            im2[t] = vfma(hc2, i, ns2*vswap(r));
        }
    } else {
        constexpr int m = JM>>1, HB = hbit(m);
        #pragma unroll
        for (int t=0;t<16;++t){
            if (t & HB) continue;
            const int t2 = t ^ m;
            v2f ru=re2[t], iu=im2[t], rv=re2[t2], iv=im2[t2];
            re2[t ] = vfma(hc2, ru, hs2*msw<JM&1>(iv));
            im2[t ] = vfma(hc2, iu, ns2*msw<JM&1>(rv));
            re2[t2] = vfma(hc2, rv, hs2*msw<JM&1>(iu));
            im2[t2] = vfma(hc2, iv, ns2*msw<JM&1>(ru));
        }
    }
}

// ---- RX, partner in another lane via ds_bpermute (lane bits 5/4 involved) ----
template<int LM,int JM>
__device__ __forceinline__ void rx_cross(v2f (&re2)[16], v2f (&im2)[16], float hc, float hs, int lane){
    const int addr = ((lane ^ LM) & 63) << 2;
    const v2f hc2 = vsplat(hc), hs2 = vsplat(hs), ns2 = vsplat(-hs);
    if constexpr ((JM>>1) == 0){
        #pragma unroll
        for (int t=0;t<16;++t){
            v2f r=re2[t], i=im2[t];
            v2f pi = bperm2(addr, msw<JM&1>(i));
            v2f pr = bperm2(addr, msw<JM&1>(r));
            re2[t] = vfma(hc2, r, hs2*pi);
            im2[t] = vfma(hc2, i, ns2*pr);
        }
    } else {
        constexpr int m = JM>>1, HB = hbit(m);
        #pragma unroll
        for (int t=0;t<16;++t){
            if (t & HB) continue;
            const int t2 = t ^ m;
            v2f ru=re2[t], iu=im2[t], rv=re2[t2], iv=im2[t2];
            v2f piu = bperm2(addr, msw<JM&1>(iv));
            v2f pru = bperm2(addr, msw<JM&1>(rv));
            v2f piv = bperm2(addr, msw<JM&1>(iu));
            v2f prv = bperm2(addr, msw<JM&1>(ru));
            re2[t ] = vfma(hc2, ru, hs2*piu);
            im2[t ] = vfma(hc2, iu, ns2*pru);
            re2[t2] = vfma(hc2, rv, hs2*piv);
            im2[t2] = vfma(hc2, iv, ns2*prv);
        }
    }
}

// ---- RX, partner in another lane via DPP (lane bits <=15, VALU pipe) ----
template<int LM,int JM>
__device__ __forceinline__ void rx_dpp(v2f (&re2)[16], v2f (&im2)[16], float hc, float hs){
    const v2f hc2 = vsplat(hc), hs2 = vsplat(hs), ns2 = vsplat(-hs);
    if constexpr ((JM>>1) == 0){
        #pragma unroll
        for (int t=0;t<16;++t){
            v2f r=re2[t], i=im2[t];
            v2f pi = dppx2<LM>(msw<JM&1>(i));
            v2f pr = dppx2<LM>(msw<JM&1>(r));
            re2[t] = vfma(hc2, r, hs2*pi);
            im2[t] = vfma(hc2, i, ns2*pr);
        }
    } else {
        constexpr int m = JM>>1, HB = hbit(m);
        #pragma unroll
        for (int t=0;t<16;++t){
            if (t & HB) continue;
            const int t2 = t ^ m;
            v2f ru=re2[t], iu=im2[t], rv=re2[t2], iv=im2[t2];
            v2f piu = dppx2<LM>(msw<JM&1>(iv));
            v2f pru = dppx2<LM>(msw<JM&1>(rv));
            v2f piv = dppx2<LM>(msw<JM&1>(iu));
            v2f prv = dppx2<LM>(msw<JM&1>(ru));
            re2[t ] = vfma(hc2, ru, hs2*piu);
            im2[t ] = vfma(hc2, iu, ns2*pru);
            re2[t2] = vfma(hc2, rv, hs2*piv);
            im2[t2] = vfma(hc2, iv, ns2*prv);
        }
    }
}

// ---- RX, partner in the other wave: LDS full-state exchange ----
// lds layout: v2f lds[2(wv)][32(t:0-15=re,16-31=im)][64(lane)]
template<int LM,int JM>
__device__ __forceinline__ void rx_wave(v2f (&re2)[16], v2f (&im2)[16], float hc, float hs,
                                        int lane, int wv, v2f* lds){
    const v2f hc2 = vsplat(hc), hs2 = vsplat(hs), ns2 = vsplat(-hs);
    v2f* wr = lds + (wv*32)*64 + lane;
    #pragma unroll
    for (int t=0;t<16;++t){ wr[t*64] = re2[t]; wr[(16+t)*64] = im2[t]; }
    __syncthreads();
    const v2f* rd = lds + ((wv^1)*32)*64 + ((lane ^ LM) & 63);
    constexpr int m = JM>>1;
    #pragma unroll
    for (int t=0;t<16;++t){
        v2f pr = msw<JM&1>(rd[(t^m)*64]);
        v2f pi = msw<JM&1>(rd[(16+(t^m))*64]);
        re2[t] = vfma(hc2, re2[t], hs2*pi);
        im2[t] = vfma(hc2, im2[t], ns2*pr);
    }
    __syncthreads();
}

// ---- unified RX dispatch on the wire-space mask M ----
template<int M>
__device__ __forceinline__ void rx_gate(v2f (&re2)[16], v2f (&im2)[16], float hc, float hs,
                                        int lane, int wv, v2f* lds){
    constexpr int LM = laneOf(M), JM = jOf(M);
    if constexpr (M & 1)       rx_wave<LM,JM>(re2,im2,hc,hs,lane,wv,lds);   // wire0 -> cross-wave
    else if constexpr (M & 6)  rx_cross<LM,JM>(re2,im2,hc,hs,lane);         // wire1/2 -> bperm
    else if constexpr (LM)     rx_dpp<LM,JM>(re2,im2,hc,hs);                // wires3..6 -> DPP
    else                       rx_local<JM>(re2,im2,hc,hs);                 // j-only
}

// ---- RZ (diagonal) ----
template<int RW>
__device__ __forceinline__ void rz_gate(v2f (&re2)[16], v2f (&im2)[16], float hc, float hs,
                                        int lane, int wv){
    constexpr int LM = laneOf(RW), JM = jOf(RW), WV = RW & 1;
    int par = __popc(lane & LM);
    if constexpr (WV) par ^= wv;
    const float hp = (par & 1) ? -hs : hs;
    const float hq = (JM & 1) ? -hp : hp;
    v2f A;  A.x = hp;   A.y = hq;
    v2f nA; nA.x = -hp; nA.y = -hq;
    const v2f hc2 = vsplat(hc);
    constexpr int m = JM >> 1;
    #pragma unroll
    for (int t=0;t<16;++t){
        const bool odd = __builtin_popcount(t & m) & 1;   // compile-time
        const v2f SV = odd ? nA : A;
        const v2f SN = odd ? A : nA;
        v2f r = re2[t], i = im2[t];
        re2[t] = vfma(hc2, r, SV*i);
        im2[t] = vfma(hc2, i, SN*r);
    }
}

template<int L,int W>
__device__ __forceinline__ void wire_gates(v2f (&re2)[16], v2f (&im2)[16],
                                           const float4* __restrict__ tbl,
                                           int lane, int wv, v2f* lds){
    const float4 t = tbl[(L-1)*NQ + W];       // uniform -> s_load_dwordx4
    rx_gate<Mwire(L,W)>(re2,im2,t.x,t.y,lane,wv,lds);
    rz_gate<Rwire(L,W)>(re2,im2,t.z,t.w,lane,wv);
    if constexpr (W+1 < NQ) wire_gates<L,W+1>(re2,im2,tbl,lane,wv,lds);
}

template<int W>
__device__ __forceinline__ void init_rx(v2f (&re2)[16], v2f (&im2)[16],
                                        const float* __restrict__ xb,
                                        int lane, int wv, v2f* lds){
    float hs, hc;
    __sincosf(xb[W]*1.5707963267948966f, &hs, &hc);
    rx_gate<(1<<W)>(re2,im2,hc,hs,lane,wv,lds);
    if constexpr (W+1 < NQ) init_rx<W+1>(re2,im2,xb,lane,wv,lds);
}

template<int L>
__device__ __forceinline__ void run_layers(v2f (&re2)[16], v2f (&im2)[16],
                                           const float4* __restrict__ tbl,
                                           int lane, int wv, v2f* lds){
    wire_gates<L,0>(re2,im2,tbl,lane,wv,lds);
    if constexpr (L < NLAYERS) run_layers<L+1>(re2,im2,tbl,lane,wv,lds);
}

__global__ void prep_kernel(const float* __restrict__ P, float4* __restrict__ tbl){
    const int i = threadIdx.x;
    if (i < NLAYERS*NQ){
        float4 v;
        __sincosf(P[2*i]   * 0.5f, &v.y, &v.x);   // RX: (cos, sin)
        __sincosf(P[2*i+1] * 0.5f, &v.w, &v.z);   // RZ: (cos, sin)
        tbl[i] = v;
    }
}

__global__ __launch_bounds__(128, 2) void qnn_kernel(const float* __restrict__ x,
                                                     const float4* __restrict__ tbl,
                                                     const float* __restrict__ Wm,
                                                     float* __restrict__ out)
{
    __shared__ v2f lds[2*32*64];
    const int lane = threadIdx.x & 63;
    const int wv   = threadIdx.x >> 6;
    const int b    = blockIdx.x;

    v2f re2[16], im2[16];
    #pragma unroll
    for (int t=0;t<16;++t){ re2[t] = vsplat(0.f); im2[t] = vsplat(0.f); }
    if (threadIdx.x == 0) re2[0].x = 1.0f;

    init_rx<0>(re2, im2, x + b*NQ, lane, wv, lds);
    run_layers<1>(re2, im2, tbl, lane, wv, lds);

    // ---- PauliZ expvals; final L = P^8 => row_w = e_w ^ e_{w-8} ----
    v2f S = vsplat(0.f), S7 = vsplat(0.f), S8 = vsplat(0.f), S9 = vsplat(0.f), S10 = vsplat(0.f);
    #pragma unroll
    for (int t=0;t<16;++t){
        v2f p2 = vfma(re2[t], re2[t], im2[t]*im2[t]);
        S += p2;
        S7  += (t&8)? -p2 : p2;   // wire 7  (j bit4)
        S8  += (t&4)? -p2 : p2;   // wire 8  (j bit3)
        S9  += (t&2)? -p2 : p2;   // wire 9  (j bit2)
        S10 += (t&1)? -p2 : p2;   // wire 10 (j bit1)
    }
    const float s0   = S.x + S.y;
    const float sw7  = S7.x + S7.y;
    const float sw8  = S8.x + S8.y;
    const float sw9  = S9.x + S9.y;
    const float sw10 = S10.x + S10.y;
    const float sw11 = S.x - S.y;             // wire 11 (j bit0 = component)

    float z[12];
    z[0] = wv ? -s0 : s0;
    #pragma unroll
    for (int w=1; w<=6; ++w) z[w] = ((lane >> (6-w)) & 1) ? -s0 : s0;
    z[7]  = sw7;
    z[8]  = wv            ? -sw8  : sw8;      // ^ wire0
    z[9]  = ((lane>>5)&1) ? -sw9  : sw9;      // ^ wire1
    z[10] = ((lane>>4)&1) ? -sw10 : sw10;     // ^ wire2
    z[11] = ((lane>>3)&1) ? -sw11 : sw11;     // ^ wire3

    #pragma unroll
    for (int m=1; m<64; m<<=1){
        #pragma unroll
        for (int w=0; w<12; ++w) z[w] += __shfl_xor(z[w], m, 64);
    }

    float* sh = (float*)lds;
    if (lane == 0){
        #pragma unroll
        for (int w=0; w<12; ++w) sh[wv*12 + w] = z[w];
    }
    __syncthreads();
    if (wv == 0){
        float t = 0.f;
        if (lane < 12){
            #pragma unroll
            for (int w=0; w<12; ++w){
                float zz = sh[w] + sh[12+w];
                t = fmaf(zz, Wm[w*12 + lane], t);
            }
            t = fmaxf(t, 0.f);
        }
        #pragma unroll
        for (int m=1; m<16; m<<=1) t += __shfl_xor(t, m, 64);
        if (lane == 0) out[b] = t;
    }
}

extern "C" void kernel_launch(void* const* d_in, const int* in_sizes, int n_in,
                              void* d_out, int out_size, void* d_ws, size_t ws_size,
                              hipStream_t stream) {
    const float* x  = (const float*)d_in[0];
    const float* P  = (const float*)d_in[1];
    const float* Wm = (const float*)d_in[2];
    float* out = (float*)d_out;
    float4* tbl = (float4*)d_ws;   // 96 * 16 B = 1536 B
    prep_kernel<<<1, 128, 0, stream>>>(P, tbl);
    qnn_kernel<<<BATCH, 128, 0, stream>>>(x, tbl, Wm, out);
}